// Round 1
// baseline (1306.768 us; speedup 1.0000x reference)
//
#include <hip/hip_runtime.h>
#include <cstdint>

// Additive attention pooling, fused single-pass with online softmax.
// B=256 blocks (one per batch), 16 waves/block, wave handles t = w (mod 16).
// Lane owns 8 contiguous u-columns (lane*8 .. lane*8+7) -> U=512 per wave.

#define NW    16            // waves per block
#define BLOCK (NW * 64)     // 1024 threads
#define UDIM  512

__global__ __launch_bounds__(BLOCK, 1)
void attn_pool_fused(const float* __restrict__ x,
                     const float* __restrict__ Wv,
                     const float* __restrict__ bv,
                     float* __restrict__ out, int T) {
    const int bidx = blockIdx.x;
    const int tid  = threadIdx.x;
    const int w    = tid >> 6;     // wave id 0..NW-1
    const int lane = tid & 63;
    const int u0   = lane << 3;    // 8 floats per lane

    // Per-lane W fragment (loaded once).
    const float4* wp  = (const float4*)(Wv + u0);
    const float4  wA  = wp[0];
    const float4  wB  = wp[1];

    const float* xb = x + (size_t)bidx * (size_t)T * UDIM;

    // Online-softmax state. Scores are tanh-bounded in (-1,1), so m=-1 is a
    // valid lower bound -> no -inf handling needed.
    float m = -1.0f, l = 0.0f;
    float o0=0.f,o1=0.f,o2=0.f,o3=0.f,o4=0.f,o5=0.f,o6=0.f,o7=0.f;

    int t = w;
    const float4* p0 = (const float4*)(xb + (size_t)t * UDIM + u0);
    float4 c0 = p0[0];
    float4 c1 = p0[1];

    const int iters = T / NW;      // T=2048, NW=16 -> 128
    for (int i = 0; i < iters; ++i) {
        // Prefetch next row into registers (branchless clamp on last iter).
        int tn = t + NW;
        int tf = (tn < T) ? tn : t;
        const float4* pn = (const float4*)(xb + (size_t)tf * UDIM + u0);
        float4 n0 = pn[0];
        float4 n1 = pn[1];

        // Per-lane partial dot of x[b,t,:] . W
        float d = c0.x*wA.x + c0.y*wA.y + c0.z*wA.z + c0.w*wA.w
                + c1.x*wB.x + c1.y*wB.y + c1.z*wB.z + c1.w*wB.w;
        // Wave-wide (64-lane) butterfly reduction.
        #pragma unroll
        for (int off = 32; off >= 1; off >>= 1)
            d += __shfl_xor(d, off, 64);

        float s  = d + bv[t];
        // tanh(s) = (e^{2s}-1)/(e^{2s}+1); |s| <~ 10 here, no overflow.
        float ex = __expf(2.0f * s);
        float e  = (ex - 1.0f) / (ex + 1.0f);

        float mn = fmaxf(m, e);
        float sc = __expf(m - mn);   // rescale of old accumulator
        float pr = __expf(e - mn);   // weight of current timestep
        l  = l * sc + pr;
        o0 = o0 * sc + pr * c0.x;
        o1 = o1 * sc + pr * c0.y;
        o2 = o2 * sc + pr * c0.z;
        o3 = o3 * sc + pr * c0.w;
        o4 = o4 * sc + pr * c1.x;
        o5 = o5 * sc + pr * c1.y;
        o6 = o6 * sc + pr * c1.z;
        o7 = o7 * sc + pr * c1.w;
        m = mn;

        c0 = n0; c1 = n1;
        t = tn;
    }

    // Merge the NW per-wave online-softmax states through LDS.
    __shared__ float sm_m[NW];
    __shared__ float sm_l[NW];
    __shared__ float sm_o[NW][UDIM];   // 32 KiB
    if (lane == 0) { sm_m[w] = m; sm_l[w] = l; }
    float4* so = (float4*)&sm_o[w][u0];
    so[0] = make_float4(o0, o1, o2, o3);
    so[1] = make_float4(o4, o5, o6, o7);
    __syncthreads();

    if (tid < UDIM) {
        float M = -1.0f;
        #pragma unroll
        for (int j = 0; j < NW; ++j) M = fmaxf(M, sm_m[j]);
        float L = 0.0f, acc = 0.0f;
        #pragma unroll
        for (int j = 0; j < NW; ++j) {
            float s = __expf(sm_m[j] - M);
            L   += s * sm_l[j];
            acc += s * sm_o[j][tid];
        }
        out[(size_t)bidx * UDIM + tid] = acc / L;
    }
}

extern "C" void kernel_launch(void* const* d_in, const int* in_sizes, int n_in,
                              void* d_out, int out_size, void* d_ws, size_t ws_size,
                              hipStream_t stream) {
    const float* x  = (const float*)d_in[0];   // (B, T, U) fp32
    const float* W  = (const float*)d_in[1];   // (U, 1)    fp32
    const float* bb = (const float*)d_in[2];   // (T, 1)    fp32
    float* out      = (float*)d_out;           // (B, U)    fp32

    const int U = in_sizes[1];                 // 512
    const int T = in_sizes[2];                 // 2048
    const int B = in_sizes[0] / (T * U);       // 256
    (void)U; (void)n_in; (void)out_size; (void)d_ws; (void)ws_size;

    attn_pool_fused<<<B, BLOCK, 0, stream>>>(x, W, bb, out, T);
}